// Round 8
// baseline (196.383 us; speedup 1.0000x reference)
//
#include <hip/hip_runtime.h>
#include <hip/hip_bf16.h>
#include <cstdint>

// Problem constants
#define CIN   256
#define COUT  256
#define NB    8
#define NT    16
#define NH    28
#define NW    28
#define HP    30
#define WP    30

#define XM_ELEMS   ((size_t)NB * NT * HP * WP * CIN)   // 29,491,200 bf16
#define XM_BYTES   (XM_ELEMS * 2)

typedef __bf16 bf16x8 __attribute__((ext_vector_type(8)));
typedef float  f32x4  __attribute__((ext_vector_type(4)));

#define AS1 __attribute__((address_space(1)))
#define AS3 __attribute__((address_space(3)))

static __device__ __forceinline__ unsigned short f2bf(float f) {
    __hip_bfloat16 h = __float2bfloat16(f);
    return __builtin_bit_cast(unsigned short, h);
}

// ---------------------------------------------------------------------------
// Pass 1: xm[b][t][hp][wp][ci] = bf16(x[b][ci][t][h][w] * alpha[b][ci][t])
// ---------------------------------------------------------------------------
__global__ void modulate_kernel(const float* __restrict__ x,
                                const float* __restrict__ alpha,
                                unsigned short* __restrict__ xm) {
    const int ci = threadIdx.x;
    const int blk = blockIdx.x;
    const int hp = blk % 30;
    const int bt = blk / 30;
    unsigned short* row = xm + (size_t)(bt * 900 + hp * 30) * 256;
    if (hp == 0 || hp == 29) {
        #pragma unroll
        for (int wp = 0; wp < 30; ++wp) row[wp * 256 + ci] = 0;
        return;
    }
    const int t = bt & 15, b = bt >> 4;
    const int h = hp - 1;
    const float a = alpha[(b * CIN + ci) * NT + t];
    const float* xrow = x + ((size_t)((b * CIN + ci) * NT + t) * NH + h) * NW;
    row[ci] = 0;
    row[29 * 256 + ci] = 0;
    const float4* xv = (const float4*)xrow;
    #pragma unroll
    for (int q = 0; q < 7; ++q) {
        float4 v = xv[q];
        row[(q * 4 + 1) * 256 + ci] = f2bf(v.x * a);
        row[(q * 4 + 2) * 256 + ci] = f2bf(v.y * a);
        row[(q * 4 + 3) * 256 + ci] = f2bf(v.z * a);
        row[(q * 4 + 4) * 256 + ci] = f2bf(v.w * a);
    }
}

// ---------------------------------------------------------------------------
// Pass 2: wB[tap][co][ci] = bf16(weight[co][ci][tap])
// ---------------------------------------------------------------------------
__global__ void repack_w_kernel(const float* __restrict__ w,
                                unsigned short* __restrict__ wB) {
    const int ci = threadIdx.x;
    const int tap = blockIdx.x >> 8;
    const int co  = blockIdx.x & 255;
    wB[((tap * 256 + co) * 256) + ci] = f2bf(w[(co * 256 + ci) * 9 + tap]);
}

// ---------------------------------------------------------------------------
// Pass 3: 128(co) x 128(n) implicit GEMM, BK=32, K=2304 = 72 kt, TAP-INNER
// order (L2-hot). co-split 2 -> grid = 2 x 784 = 1568 blocks of 256 thr
// (4 waves, 2M x 2N, wave tile 64x64, acc 4x4 = 64 AGPR). ~140 regs via
// __launch_bounds__(256,3) -> 3 waves/SIMD -> 3 INDEPENDENT blocks/CU
// co-resident: block-level TLP hides the per-kt serial chain (the R5 idea
// with R6's traffic shape). LDS 32KB dbuf, 64B rows, swizzle
// col ^= (row>>1)&3, pre-swizzled global_load_lds source. 4 loads/wave/kt;
// VMW(4) drains a stage issued 2 kt-bodies ago.
// ---------------------------------------------------------------------------

#define BAR()    __builtin_amdgcn_s_barrier()
#define LGKM0()  asm volatile("s_waitcnt lgkmcnt(0)" ::: "memory")
#define VMW(N)   asm volatile("s_waitcnt vmcnt(" #N ")" ::: "memory")
#define SCHED0() __builtin_amdgcn_sched_barrier(0)
#define PRIO(x)  __builtin_amdgcn_s_setprio(x)

// stage kt' (parity P): A 128x32 (2 loads/wave), B 128x32 (2 loads/wave)
#define STAGE(P, aOffE, bOffE) do {                                          \
    _Pragma("unroll") for (int c_ = 0; c_ < 2; ++c_)                         \
        __builtin_amdgcn_global_load_lds(                                    \
            (const AS1 void*)(aSrcLane + (aOffE) + c_ * 4096),               \
            (AS3 void*)(lds + (P)*8192 + wv*2048 + c_*1024 + lane*16),       \
            16, 0, 0);                                                       \
    _Pragma("unroll") for (int c_ = 0; c_ < 2; ++c_)                         \
        __builtin_amdgcn_global_load_lds(                                    \
            (const AS1 void*)(bL[c_] + (bOffE)),                             \
            (AS3 void*)(lds + 16384 + (P)*8192 + wv*2048 + c_*1024 + lane*16),\
            16, 0, 0);                                                       \
} while (0)

// stage for next kt-target, advancing tap2/cic2 (call exactly once per kt)
#define STAGE_NEXT(P) do {                                                   \
    const int kh2 = (tap2 * 11) >> 5;                                        \
    const int kw2 = tap2 - 3 * kh2;                                          \
    STAGE(P, tap2 * 65536 + cic2 * 32,                                       \
             ((kh2 - 1) * 30 + (kw2 - 1)) * 256 + cic2 * 32);                \
    if (++tap2 == 9) { tap2 = 0; ++cic2; }                                   \
} while (0)

#define READF(P) do {                                                        \
    _Pragma("unroll") for (int m_ = 0; m_ < 4; ++m_)                         \
        fa[m_] = *(const bf16x8*)(lds + (P)*8192 + aRdBase + m_*1024);       \
    _Pragma("unroll") for (int f_ = 0; f_ < 4; ++f_)                         \
        fb[f_] = *(const bf16x8*)(lds + 16384 + (P)*8192 + bRdBase + f_*1024);\
} while (0)

#define MFMA16() do {                                                        \
    _Pragma("unroll") for (int m_ = 0; m_ < 4; ++m_)                         \
    _Pragma("unroll") for (int f_ = 0; f_ < 4; ++f_)                         \
        acc[m_][f_] = __builtin_amdgcn_mfma_f32_16x16x32_bf16(               \
            fb[f_], fa[m_], acc[m_][f_], 0, 0, 0);                           \
} while (0)

__global__ __launch_bounds__(256, 3) void conv_gemm_kernel(
    const unsigned short* __restrict__ xm,
    const unsigned short* __restrict__ wB,
    float* __restrict__ out) {
    __shared__ __align__(1024) char lds[32768];

    const int tid  = threadIdx.x;
    const int wv   = tid >> 6;             // 0..3
    const int lane = tid & 63;
    const int l15  = lane & 15;
    const int bx   = blockIdx.x;
    const int co0  = (bx & 1) << 7;        // 0 or 128
    const int n0   = (bx >> 1) << 7;       // n-tile * 128
    const int wm   = wv >> 1;              // 0..1 co half within block
    const int wn   = wv & 1;               // 0..1 n half within block

    // ---- staging sources (pre-swizzled ci offset; inverse of read swizzle) ----
    const int swzE = 8 * ((lane & 3) ^ ((lane >> 3) & 3));
    const unsigned short* aSrcLane =
        wB + (co0 + wv * 32 + (lane >> 2)) * 256 + swzE;

    const unsigned short* bL[2];
    #pragma unroll
    for (int c_ = 0; c_ < 2; ++c_) {
        const int nl = wv * 32 + c_ * 16 + (lane >> 2);   // 0..127, all real
        const int n  = n0 + nl;
        const int w_ = n % 28, h_ = (n / 28) % 28, bt = n / 784;
        bL[c_] = xm + (size_t)((bt * 30 + h_ + 1) * 30 + (w_ + 1)) * 256 + swzE;
    }

    // ---- fragment read bases (byte offsets; swizzle col ^= (row>>1)&3) ----
    const int readSwz = ((lane >> 4) ^ ((l15 >> 1) & 3)) << 4;
    const int aRdBase = (wm * 64 + l15) * 64 + readSwz;   // + P*8192 + m*1024
    const int bRdBase = (wn * 64 + l15) * 64 + readSwz;   // +16384 + P*8192 + f*1024

    f32x4 acc[4][4];
    #pragma unroll
    for (int i = 0; i < 4; ++i)
        #pragma unroll
        for (int j = 0; j < 4; ++j) acc[i][j] = f32x4{0.f, 0.f, 0.f, 0.f};

    bf16x8 fa[4], fb[4];

    int tap2 = 0, cic2 = 0;
    // ---- prologue: kt=0 -> buf0, kt=1 -> buf1 ----
    STAGE_NEXT(0);                 // S(0)
    STAGE_NEXT(1);                 // S(1)

    // per kt: VMW(4) drains S(kt) (issued 2 bodies ago); BAR publishes it.
    #pragma unroll 1
    for (int kt = 0; kt < 71; ++kt) {
        const int p = kt & 1;
        VMW(4);
        SCHED0();
        BAR();             // all waves' S(kt) landed -> buf p valid
        SCHED0();
        READF(p);
        LGKM0();           // my frags in regs
        SCHED0();
        BAR();             // all waves done reading buf p -> safe to restage
        if (kt < 70) STAGE_NEXT(p);    // S(kt+2) -> buf p
        PRIO(1); MFMA16(); PRIO(0);
    }
    // ---- peeled kt=71 (buf1): exact drain ----
    VMW(0);
    SCHED0();
    BAR();
    SCHED0();
    READF(1);
    LGKM0();
    SCHED0();
    PRIO(1); MFMA16(); PRIO(0);

    // ---- C-write: lane holds 4 consecutive n (rows) at one co (col) ----
    #pragma unroll
    for (int f = 0; f < 4; ++f) {
        const int n  = n0 + wn * 64 + f * 16 + ((lane >> 4) << 2);
        const int bt = n / 784;
        const int hw = n - bt * 784;
        const int b = bt >> 4, t = bt & 15;
        float* obase = out + ((size_t)(b * 256) * 16 + t) * 784 + hw;
        #pragma unroll
        for (int m = 0; m < 4; ++m) {
            const int co = co0 + wm * 64 + m * 16 + l15;
            *(f32x4*)(obase + (size_t)co * 12544) = acc[m][f];
        }
    }
}

// ---------------------------------------------------------------------------
extern "C" void kernel_launch(void* const* d_in, const int* in_sizes, int n_in,
                              void* d_out, int out_size, void* d_ws, size_t ws_size,
                              hipStream_t stream) {
    const float* x      = (const float*)d_in[0];
    const float* alpha  = (const float*)d_in[1];
    const float* weight = (const float*)d_in[2];
    float* out = (float*)d_out;

    unsigned short* xm = (unsigned short*)d_ws;
    unsigned short* wB = (unsigned short*)((char*)d_ws + XM_BYTES);

    modulate_kernel<<<dim3(NB * NT * HP), dim3(256), 0, stream>>>(x, alpha, xm);
    repack_w_kernel<<<dim3(9 * 256), dim3(256), 0, stream>>>(weight, wB);
    conv_gemm_kernel<<<dim3(1568), dim3(256), 0, stream>>>(xm, wB, out);
}

// Round 9
// 166.978 us; speedup vs baseline: 1.1761x; 1.1761x over previous
//
#include <hip/hip_runtime.h>
#include <hip/hip_bf16.h>
#include <cstdint>

// Problem constants
#define CIN   256
#define COUT  256
#define NB    8
#define NT    16
#define NH    28
#define NW    28
#define HP    30
#define WP    30

#define XM_ELEMS   ((size_t)NB * NT * HP * WP * CIN)   // 29,491,200 bf16
#define XM_BYTES   (XM_ELEMS * 2)

typedef __bf16 bf16x8 __attribute__((ext_vector_type(8)));
typedef float  f32x4  __attribute__((ext_vector_type(4)));

#define AS1 __attribute__((address_space(1)))
#define AS3 __attribute__((address_space(3)))

static __device__ __forceinline__ unsigned short f2bf(float f) {
    __hip_bfloat16 h = __float2bfloat16(f);
    return __builtin_bit_cast(unsigned short, h);
}

// ---------------------------------------------------------------------------
// Pass 1: xm[b][t][hp][wp][ci] = bf16(x[b][ci][t][h][w] * alpha[b][ci][t])
// ---------------------------------------------------------------------------
__global__ void modulate_kernel(const float* __restrict__ x,
                                const float* __restrict__ alpha,
                                unsigned short* __restrict__ xm) {
    const int ci = threadIdx.x;
    const int blk = blockIdx.x;
    const int hp = blk % 30;
    const int bt = blk / 30;
    unsigned short* row = xm + (size_t)(bt * 900 + hp * 30) * 256;
    if (hp == 0 || hp == 29) {
        #pragma unroll
        for (int wp = 0; wp < 30; ++wp) row[wp * 256 + ci] = 0;
        return;
    }
    const int t = bt & 15, b = bt >> 4;
    const int h = hp - 1;
    const float a = alpha[(b * CIN + ci) * NT + t];
    const float* xrow = x + ((size_t)((b * CIN + ci) * NT + t) * NH + h) * NW;
    row[ci] = 0;
    row[29 * 256 + ci] = 0;
    const float4* xv = (const float4*)xrow;
    #pragma unroll
    for (int q = 0; q < 7; ++q) {
        float4 v = xv[q];
        row[(q * 4 + 1) * 256 + ci] = f2bf(v.x * a);
        row[(q * 4 + 2) * 256 + ci] = f2bf(v.y * a);
        row[(q * 4 + 3) * 256 + ci] = f2bf(v.z * a);
        row[(q * 4 + 4) * 256 + ci] = f2bf(v.w * a);
    }
}

// ---------------------------------------------------------------------------
// Pass 2: wB[tap][co][ci] = bf16(weight[co][ci][tap])
// ---------------------------------------------------------------------------
__global__ void repack_w_kernel(const float* __restrict__ w,
                                unsigned short* __restrict__ wB) {
    const int ci = threadIdx.x;
    const int tap = blockIdx.x >> 8;
    const int co  = blockIdx.x & 255;
    wB[((tap * 256 + co) * 256) + ci] = f2bf(w[(co * 256 + ci) * 9 + tap]);
}

// ---------------------------------------------------------------------------
// Pass 3: 256(co) x 224(n) implicit GEMM, BK=32, K=2304 = 72 kt, TAP-INNER
// order (L2-hot, R6-verified). grid = 448, block = 512 (8 waves, 4M x 2N,
// wave tile 64co x 112n, acc 4x7 = 112 AGPR). R7's 1-barrier/kt schedule:
// register double-buffered fragment sets -- frags(kt+1) ds_reads issue
// before MFMA(kt), LGKM0 after; one BAR + one VMW(0) per kt (vs R3's 4
// BAR-pairs per BK=64 kt). Dual frag sets 88 VGPR -> ~220 regs total,
// 2 waves/SIMD, 1 block/CU (LDS 64KB dbuf). 64B LDS rows, swizzle
// slot ^= (row>>1)&3 (0-conflict, R6/R7-verified), pre-swizzled
// global_load_lds source.
// ---------------------------------------------------------------------------

#define BAR()    __builtin_amdgcn_s_barrier()
#define LGKM0()  asm volatile("s_waitcnt lgkmcnt(0)" ::: "memory")
#define VMW(N)   asm volatile("s_waitcnt vmcnt(" #N ")" ::: "memory")
#define SCHED0() __builtin_amdgcn_sched_barrier(0)
#define PRIO(x)  __builtin_amdgcn_s_setprio(x)

// stage K-tile (tap2,cic2) into buf P: A 256x32 (2 loads/wave),
// B 256(224+dup)x32 (2 loads/wave). Advances tap2/cic2.
#define STAGE_F(P) do {                                                       \
    const int kh2 = (tap2 * 11) >> 5;                                         \
    const int kw2 = tap2 - 3 * kh2;                                           \
    const int aOff = tap2 * 65536 + cic2 * 32;                                \
    const int bOff = ((kh2 - 1) * 30 + (kw2 - 1)) * 256 + cic2 * 32;          \
    _Pragma("unroll") for (int c_ = 0; c_ < 2; ++c_)                          \
        __builtin_amdgcn_global_load_lds(                                     \
            (const AS1 void*)(aSrc + aOff + c_ * 32768),                      \
            (AS3 void*)(lds + (P)*32768 + (c_*128 + wave*16)*64 + lane*16),   \
            16, 0, 0);                                                        \
    _Pragma("unroll") for (int c_ = 0; c_ < 2; ++c_)                          \
        __builtin_amdgcn_global_load_lds(                                     \
            (const AS1 void*)(bL[c_] + bOff),                                 \
            (AS3 void*)(lds + (P)*32768 + 16384 + (c_*128 + wave*16)*64 + lane*16), \
            16, 0, 0);                                                        \
    if (++tap2 == 9) { tap2 = 0; ++cic2; }                                    \
} while (0)

#define READF(S, P) do {                                                      \
    _Pragma("unroll") for (int m_ = 0; m_ < 4; ++m_)                          \
        fa##S[m_] = *(const bf16x8*)(lds + (P)*32768 +                        \
            (wm*64 + m_*16 + l15)*64 + readSwz);                              \
    _Pragma("unroll") for (int f_ = 0; f_ < 7; ++f_)                          \
        fb##S[f_] = *(const bf16x8*)(lds + (P)*32768 + 16384 +                \
            (wn*112 + f_*16 + l15)*64 + readSwz);                             \
} while (0)

#define MFMA28(S) do {                                                        \
    _Pragma("unroll") for (int m_ = 0; m_ < 4; ++m_)                          \
    _Pragma("unroll") for (int f_ = 0; f_ < 7; ++f_)                          \
        acc[m_][f_] = __builtin_amdgcn_mfma_f32_16x16x32_bf16(                \
            fb##S[f_], fa##S[m_], acc[m_][f_], 0, 0, 0);                      \
} while (0)

__global__ __launch_bounds__(512, 2) void conv_gemm_kernel(
    const unsigned short* __restrict__ xm,
    const unsigned short* __restrict__ wB,
    float* __restrict__ out) {
    __shared__ __align__(1024) char lds[65536];   // 2 x (A 16KB + B 16KB)

    const int tid  = threadIdx.x;
    const int wave = tid >> 6;             // 0..7
    const int lane = tid & 63;
    const int l15  = lane & 15;
    const int n0   = blockIdx.x * 224;
    const int wm   = wave >> 1;            // 0..3 co quarter (64)
    const int wn   = wave & 1;             // 0..1 n half (112)

    // ---- staging sources (pre-swizzled ci slot; inverse of read swizzle) ----
    const int swzE = 8 * ((lane & 3) ^ ((lane >> 3) & 3));
    const unsigned short* aSrc = wB + (wave * 16 + (lane >> 2)) * 256 + swzE;

    const unsigned short* bL[2];
    #pragma unroll
    for (int c_ = 0; c_ < 2; ++c_) {
        int nl = c_ * 128 + wave * 16 + (lane >> 2);   // 0..255
        nl = nl > 223 ? 223 : nl;                      // pad rows duplicate
        const int n  = n0 + nl;
        const int w_ = n % 28, h_ = (n / 28) % 28, bt = n / 784;
        bL[c_] = xm + (size_t)((bt * 30 + h_ + 1) * 30 + (w_ + 1)) * 256 + swzE;
    }

    // ---- fragment read base (bytes; slot swizzle (row>>1)&3, R7-verified) ----
    const int readSwz = ((lane >> 4) ^ ((l15 >> 1) & 3)) << 4;

    f32x4 acc[4][7];
    #pragma unroll
    for (int i = 0; i < 4; ++i)
        #pragma unroll
        for (int j = 0; j < 7; ++j) acc[i][j] = f32x4{0.f, 0.f, 0.f, 0.f};

    bf16x8 faA[4], fbA[7], faB[4], fbB[7];

    int tap2 = 0, cic2 = 0;
    // ---- prologue: S(0)->buf0, S(1)->buf1; frags(0) -> set A ----
    STAGE_F(0);
    STAGE_F(1);
    VMW(4);                        // S(0) landed; S(1)'s 4 in flight
    SCHED0();
    BAR();
    READF(A, 0);                   // frags(0)
    LGKM0();

    // invariant at even-body top (K even, set A = frags(K) in regs):
    //   outstanding vmem = S(K+1)'s 4 loads -> VMW(0) exact drain
    #pragma unroll 1
    for (int it = 0; it < 35; ++it) {
        // ---- even: compute K (A), read K+1 (B), stage S(K+2)->buf0 ----
        VMW(0);
        SCHED0();
        BAR();                     // publish buf1(K+1); license restage buf0
        READF(B, 1);
        STAGE_F(0);
        SCHED0();
        PRIO(1); MFMA28(A); PRIO(0);
        LGKM0();                   // set B ready (hidden under MFMA)
        SCHED0();
        // ---- odd: compute K+1 (B), read K+2 (A), stage S(K+3)->buf1 ----
        VMW(0);
        SCHED0();
        BAR();                     // publish buf0(K+2); license restage buf1
        READF(A, 0);
        STAGE_F(1);
        SCHED0();
        PRIO(1); MFMA28(B); PRIO(0);
        LGKM0();
        SCHED0();
    }
    // ---- peel K=70,71: set A = frags(70); S(71) in flight ----
    VMW(0);
    SCHED0();
    BAR();
    READF(B, 1);                   // frags(71)
    SCHED0();
    PRIO(1); MFMA28(A); PRIO(0);
    LGKM0();
    SCHED0();
    PRIO(1); MFMA28(B); PRIO(0);

    // ---- C-write: lane holds 4 consecutive n (rows) at one co (col) ----
    #pragma unroll
    for (int f = 0; f < 7; ++f) {
        const int n  = n0 + wn * 112 + f * 16 + ((lane >> 4) << 2);
        const int bt = n / 784;
        const int hw = n - bt * 784;
        const int b = bt >> 4, t = bt & 15;
        float* obase = out + ((size_t)(b * 256) * 16 + t) * 784 + hw;
        #pragma unroll
        for (int m = 0; m < 4; ++m) {
            const int co = wm * 64 + m * 16 + l15;
            *(f32x4*)(obase + (size_t)co * 12544) = acc[m][f];
        }
    }
}

// ---------------------------------------------------------------------------
extern "C" void kernel_launch(void* const* d_in, const int* in_sizes, int n_in,
                              void* d_out, int out_size, void* d_ws, size_t ws_size,
                              hipStream_t stream) {
    const float* x      = (const float*)d_in[0];
    const float* alpha  = (const float*)d_in[1];
    const float* weight = (const float*)d_in[2];
    float* out = (float*)d_out;

    unsigned short* xm = (unsigned short*)d_ws;
    unsigned short* wB = (unsigned short*)((char*)d_ws + XM_BYTES);

    modulate_kernel<<<dim3(NB * NT * HP), dim3(256), 0, stream>>>(x, alpha, xm);
    repack_w_kernel<<<dim3(9 * 256), dim3(256), 0, stream>>>(weight, wB);
    conv_gemm_kernel<<<dim3(448), dim3(512), 0, stream>>>(xm, wB, out);
}

// Round 10
// 158.331 us; speedup vs baseline: 1.2403x; 1.0546x over previous
//
#include <hip/hip_runtime.h>
#include <hip/hip_bf16.h>
#include <cstdint>

// Problem constants
#define CIN   256
#define COUT  256
#define NB    8
#define NT    16
#define NH    28
#define NW    28
#define HP    30
#define WP    30

#define XM_ELEMS   ((size_t)NB * NT * HP * WP * CIN)   // 29,491,200 bf16
#define XM_BYTES   (XM_ELEMS * 2)

typedef __bf16 bf16x8 __attribute__((ext_vector_type(8)));
typedef float  f32x4  __attribute__((ext_vector_type(4)));

#define AS1 __attribute__((address_space(1)))
#define AS3 __attribute__((address_space(3)))

static __device__ __forceinline__ unsigned short f2bf(float f) {
    __hip_bfloat16 h = __float2bfloat16(f);
    return __builtin_bit_cast(unsigned short, h);
}

// ---------------------------------------------------------------------------
// Pass 1: xm[b][t][hp][wp][ci] = bf16(x[b][ci][t][h][w] * alpha[b][ci][t])
// ---------------------------------------------------------------------------
__global__ void modulate_kernel(const float* __restrict__ x,
                                const float* __restrict__ alpha,
                                unsigned short* __restrict__ xm) {
    const int ci = threadIdx.x;
    const int blk = blockIdx.x;
    const int hp = blk % 30;
    const int bt = blk / 30;
    unsigned short* row = xm + (size_t)(bt * 900 + hp * 30) * 256;
    if (hp == 0 || hp == 29) {
        #pragma unroll
        for (int wp = 0; wp < 30; ++wp) row[wp * 256 + ci] = 0;
        return;
    }
    const int t = bt & 15, b = bt >> 4;
    const int h = hp - 1;
    const float a = alpha[(b * CIN + ci) * NT + t];
    const float* xrow = x + ((size_t)((b * CIN + ci) * NT + t) * NH + h) * NW;
    row[ci] = 0;
    row[29 * 256 + ci] = 0;
    const float4* xv = (const float4*)xrow;
    #pragma unroll
    for (int q = 0; q < 7; ++q) {
        float4 v = xv[q];
        row[(q * 4 + 1) * 256 + ci] = f2bf(v.x * a);
        row[(q * 4 + 2) * 256 + ci] = f2bf(v.y * a);
        row[(q * 4 + 3) * 256 + ci] = f2bf(v.z * a);
        row[(q * 4 + 4) * 256 + ci] = f2bf(v.w * a);
    }
}

// ---------------------------------------------------------------------------
// Pass 2: wB[tap][co][ci] = bf16(weight[co][ci][tap])
// ---------------------------------------------------------------------------
__global__ void repack_w_kernel(const float* __restrict__ w,
                                unsigned short* __restrict__ wB) {
    const int ci = threadIdx.x;
    const int tap = blockIdx.x >> 8;
    const int co  = blockIdx.x & 255;
    wB[((tap * 256 + co) * 256) + ci] = f2bf(w[(co * 256 + ci) * 9 + tap]);
}

// ---------------------------------------------------------------------------
// Pass 3: 256(co) x 224(n) implicit GEMM, BK=32, K=2304 = 72 kt, TAP-INNER
// (L2-hot, FETCH~45MB verified R9). grid=448, block=512 (8 waves, 4Mx2N,
// wave 64co x 112n, acc 4x7 = 112 AGPR). R9's 1-BAR/kt reg-dbuf schedule
// PLUS 3-deep LDS staging with counted VMW(4) -- never vmcnt(0) in the
// main loop (T4). Body j: VMW(4) drains S(j+1) issued TWO bodies earlier
// (L2 latency + LDS-write queue fully hidden); BAR; READF frags(j+1);
// STAGE S(j+3) -> buf j%3; MFMA(frags(j)); LGKM0. Unroll x6 (buf%3 x
// set%2 compile-time). LDS 96KB = 3 x (A 16KB + B 16KB). 64B rows,
// swizzle slot ^= (row>>1)&3 (0-conflict verified), pre-swizzled
// global_load_lds source.
// ---------------------------------------------------------------------------

#define BAR()    __builtin_amdgcn_s_barrier()
#define LGKM0()  asm volatile("s_waitcnt lgkmcnt(0)" ::: "memory")
#define VMW(N)   asm volatile("s_waitcnt vmcnt(" #N ")" ::: "memory")
#define SCHED0() __builtin_amdgcn_sched_barrier(0)
#define PRIO(x)  __builtin_amdgcn_s_setprio(x)

// stage K-tile (tap2,cic2) into buf P (P in {0,1,2}): A 256x32 (2 loads/
// wave), B 224(+dup)x32 (2 loads/wave). Advances tap2/cic2.
#define STAGE_F(P) do {                                                       \
    const int kh2 = (tap2 * 11) >> 5;                                         \
    const int kw2 = tap2 - 3 * kh2;                                           \
    const int aOff = tap2 * 65536 + cic2 * 32;                                \
    const int bOff = ((kh2 - 1) * 30 + (kw2 - 1)) * 256 + cic2 * 32;          \
    _Pragma("unroll") for (int c_ = 0; c_ < 2; ++c_)                          \
        __builtin_amdgcn_global_load_lds(                                     \
            (const AS1 void*)(aSrc + aOff + c_ * 32768),                      \
            (AS3 void*)(lds + (P)*32768 + (c_*128 + wave*16)*64 + lane*16),   \
            16, 0, 0);                                                        \
    _Pragma("unroll") for (int c_ = 0; c_ < 2; ++c_)                          \
        __builtin_amdgcn_global_load_lds(                                     \
            (const AS1 void*)(bL[c_] + bOff),                                 \
            (AS3 void*)(lds + (P)*32768 + 16384 + (c_*128 + wave*16)*64 + lane*16), \
            16, 0, 0);                                                        \
    if (++tap2 == 9) { tap2 = 0; ++cic2; }                                    \
} while (0)

#define READF(S, P) do {                                                      \
    _Pragma("unroll") for (int m_ = 0; m_ < 4; ++m_)                          \
        fa##S[m_] = *(const bf16x8*)(lds + (P)*32768 +                        \
            (wm*64 + m_*16 + l15)*64 + readSwz);                              \
    _Pragma("unroll") for (int f_ = 0; f_ < 7; ++f_)                          \
        fb##S[f_] = *(const bf16x8*)(lds + (P)*32768 + 16384 +                \
            (wn*112 + f_*16 + l15)*64 + readSwz);                             \
} while (0)

#define MFMA28(S) do {                                                        \
    _Pragma("unroll") for (int m_ = 0; m_ < 4; ++m_)                          \
    _Pragma("unroll") for (int f_ = 0; f_ < 7; ++f_)                          \
        acc[m_][f_] = __builtin_amdgcn_mfma_f32_16x16x32_bf16(                \
            fb##S[f_], fa##S[m_], acc[m_][f_], 0, 0, 0);                      \
} while (0)

// body j: compute set CS = frags(j); read frags(j+1) -> set NS from buf
// NBUF=(j+1)%3; stage S(j+3) into SBUF=j%3. VMW(4) drains S(j+1).
#define BODY_S(CS, NS, NBUF, SBUF) do {                                       \
    VMW(4);                                                                   \
    SCHED0();                                                                 \
    BAR();                                                                    \
    READF(NS, NBUF);                                                          \
    STAGE_F(SBUF);                                                            \
    SCHED0();                                                                 \
    PRIO(1); MFMA28(CS); PRIO(0);                                             \
    LGKM0();                                                                  \
    SCHED0();                                                                 \
} while (0)

// no-stage body (tail); VMN = vmcnt target
#define BODY_N(CS, NS, NBUF, VMN) do {                                        \
    VMW(VMN);                                                                 \
    SCHED0();                                                                 \
    BAR();                                                                    \
    READF(NS, NBUF);                                                          \
    SCHED0();                                                                 \
    PRIO(1); MFMA28(CS); PRIO(0);                                             \
    LGKM0();                                                                  \
    SCHED0();                                                                 \
} while (0)

__global__ __launch_bounds__(512, 2) void conv_gemm_kernel(
    const unsigned short* __restrict__ xm,
    const unsigned short* __restrict__ wB,
    float* __restrict__ out) {
    __shared__ __align__(1024) char lds[98304];   // 3 x (A 16KB + B 16KB)

    const int tid  = threadIdx.x;
    const int wave = tid >> 6;             // 0..7
    const int lane = tid & 63;
    const int l15  = lane & 15;
    const int n0   = blockIdx.x * 224;
    const int wm   = wave >> 1;            // 0..3 co quarter (64)
    const int wn   = wave & 1;             // 0..1 n half (112)

    // ---- staging sources (pre-swizzled ci slot; inverse of read swizzle) ----
    const int swzE = 8 * ((lane & 3) ^ ((lane >> 3) & 3));
    const unsigned short* aSrc = wB + (wave * 16 + (lane >> 2)) * 256 + swzE;

    const unsigned short* bL[2];
    #pragma unroll
    for (int c_ = 0; c_ < 2; ++c_) {
        int nl = c_ * 128 + wave * 16 + (lane >> 2);   // 0..255
        nl = nl > 223 ? 223 : nl;                      // pad rows duplicate
        const int n  = n0 + nl;
        const int w_ = n % 28, h_ = (n / 28) % 28, bt = n / 784;
        bL[c_] = xm + (size_t)((bt * 30 + h_ + 1) * 30 + (w_ + 1)) * 256 + swzE;
    }

    // ---- fragment read base (bytes; slot swizzle (row>>1)&3, verified) ----
    const int readSwz = ((lane >> 4) ^ ((l15 >> 1) & 3)) << 4;

    f32x4 acc[4][7];
    #pragma unroll
    for (int i = 0; i < 4; ++i)
        #pragma unroll
        for (int j = 0; j < 7; ++j) acc[i][j] = f32x4{0.f, 0.f, 0.f, 0.f};

    bf16x8 faA[4], fbA[7], faB[4], fbB[7];

    int tap2 = 0, cic2 = 0;
    // ---- prologue: S(0)->b0, S(1)->b1, S(2)->b2; frags(0) -> set A ----
    STAGE_F(0);
    STAGE_F(1);
    STAGE_F(2);
    VMW(8);                        // my S(0) landed (S(1),S(2) in flight)
    SCHED0();
    BAR();                         // all waves' S(0) landed
    READF(A, 0);                   // frags(0)
    LGKM0();
    SCHED0();

    // main: bodies j=0..65, pattern period 6 (buf%3 x set%2)
    #pragma unroll 1
    for (int it = 0; it < 11; ++it) {
        BODY_S(A, B, 1, 0);        // j=6it+0
        BODY_S(B, A, 2, 1);        // j=6it+1
        BODY_S(A, B, 0, 2);        // j=6it+2
        BODY_S(B, A, 1, 0);        // j=6it+3
        BODY_S(A, B, 2, 1);        // j=6it+4
        BODY_S(B, A, 0, 2);        // j=6it+5
    }
    // tail: j=66..70 (stages S(69..71) at j=66..68), then peel j=71
    BODY_S(A, B, 1, 0);            // j=66: stage S(69)
    BODY_S(B, A, 2, 1);            // j=67: stage S(70)
    BODY_S(A, B, 0, 2);            // j=68: stage S(71)
    BODY_N(B, A, 1, 4);            // j=69: drain S(70)
    BODY_N(A, B, 2, 0);            // j=70: drain S(71), read frags(71)
    PRIO(1); MFMA28(B); PRIO(0);   // j=71

    // ---- C-write: lane holds 4 consecutive n (rows) at one co (col) ----
    #pragma unroll
    for (int f = 0; f < 7; ++f) {
        const int n  = n0 + wn * 112 + f * 16 + ((lane >> 4) << 2);
        const int bt = n / 784;
        const int hw = n - bt * 784;
        const int b = bt >> 4, t = bt & 15;
        float* obase = out + ((size_t)(b * 256) * 16 + t) * 784 + hw;
        #pragma unroll
        for (int m = 0; m < 4; ++m) {
            const int co = wm * 64 + m * 16 + l15;
            *(f32x4*)(obase + (size_t)co * 12544) = acc[m][f];
        }
    }
}

// ---------------------------------------------------------------------------
extern "C" void kernel_launch(void* const* d_in, const int* in_sizes, int n_in,
                              void* d_out, int out_size, void* d_ws, size_t ws_size,
                              hipStream_t stream) {
    const float* x      = (const float*)d_in[0];
    const float* alpha  = (const float*)d_in[1];
    const float* weight = (const float*)d_in[2];
    float* out = (float*)d_out;

    unsigned short* xm = (unsigned short*)d_ws;
    unsigned short* wB = (unsigned short*)((char*)d_ws + XM_BYTES);

    modulate_kernel<<<dim3(NB * NT * HP), dim3(256), 0, stream>>>(x, alpha, xm);
    repack_w_kernel<<<dim3(9 * 256), dim3(256), 0, stream>>>(weight, wB);
    conv_gemm_kernel<<<dim3(448), dim3(512), 0, stream>>>(xm, wB, out);
}